// Round 8
// baseline (774.928 us; speedup 1.0000x reference)
//
#include <hip/hip_runtime.h>

#define N_NODES 100000
#define N_EDGES 3200000
#define FEAT 256
#define HID 128
#define OUT 64
#define HOPS 3

#define NPAD 100352                      // 98*1024, >= N_NODES
#define NTOT (2 * NPAD)                  // combined s|t dst-unit space = 200704
#define NBUCK 196                        // NTOT / 1024 buckets (1024 units each)
#define CAP 36864                        // fixed bucket capacity (mean 32768, +22 sigma)
#define RPS 1028                         // rowptr stride per bucket (1024 starts + end slot)
#define EPB 2048                         // edges per block in CSR-build passes

typedef unsigned short ushort_t;

__device__ __forceinline__ float bf2f(ushort_t u) {
    return __uint_as_float(((unsigned)u) << 16);
}
__device__ __forceinline__ float bflo(unsigned u) { return __uint_as_float(u << 16); }
__device__ __forceinline__ float bfhi(unsigned u) { return __uint_as_float(u & 0xffff0000u); }
__device__ __forceinline__ unsigned pack_bf16(float a, float b) {
    unsigned ua = __float_as_uint(a);
    unsigned ub = __float_as_uint(b);
    ua += 0x7fffu + ((ua >> 16) & 1u);
    ub += 0x7fffu + ((ub >> 16) & 1u);
    return (ua >> 16) | (ub & 0xffff0000u);
}

// ---------------- weight fold: Wc = W_{src,tgt} @ Wn_half ; bc = b @ Wn_half
__global__ __launch_bounds__(64) void wcomb_k(
    const float* __restrict__ Wsrc, const float* __restrict__ Wtgt,
    const float* __restrict__ bsrc, const float* __restrict__ btgt,
    const float* __restrict__ Wn,     // [2*HID, OUT]
    float* __restrict__ Wc,           // [512, 64]
    float* __restrict__ bc)           // [128]
{
    const int blk = blockIdx.x;
    const int j = threadIdx.x;
    if (blk < 512) {
        const float* Wsel = (blk < 256) ? Wsrc : Wtgt;
        const int i = blk & 255;
        const int koff = (blk < 256) ? 0 : HID;
        float acc = 0.f;
        for (int k = 0; k < HID; ++k)
            acc = fmaf(Wsel[i * HID + k], Wn[(koff + k) * OUT + j], acc);
        Wc[blk * OUT + j] = acc;
    } else {
        const float* bsel = (blk == 512) ? bsrc : btgt;
        const int koff = (blk == 512) ? 0 : HID;
        float acc = 0.f;
        for (int k = 0; k < HID; ++k)
            acc = fmaf(bsel[k], Wn[(koff + k) * OUT + j], acc);
        bc[(blk - 512) * OUT + j] = acc;
    }
}

// ---------------- input GEMM: h0 = bf16(X @ Wc + bc) ------------------------
__global__ __launch_bounds__(256) void gemm_in(
    const float* __restrict__ X,      // [N, FEAT]
    const float* __restrict__ B,      // [FEAT, OUT] folded weights
    const float* __restrict__ bias,   // [OUT] folded bias
    ushort_t* __restrict__ h0)        // [N, OUT] bf16
{
    __shared__ __align__(16) float at[64][76];   // A transposed [kk][row]
    __shared__ __align__(16) float bs[64][OUT];  // B chunk [kk][j]
    const int tid = threadIdx.x;
    const int tx = tid & 15;          // cols tx*4 .. tx*4+3
    const int ty = tid >> 4;          // rows ty*4 .. ty*4+3
    const int row0 = blockIdx.x * 64;

    float acc[4][4];
#pragma unroll
    for (int r = 0; r < 4; ++r)
#pragma unroll
        for (int c = 0; c < 4; ++c) acc[r][c] = 0.f;

    for (int chunk = 0; chunk < 4; ++chunk) {
        const int kbase = chunk * 64;
        {
            int lc = tid & 15, lr = tid >> 4;
#pragma unroll
            for (int p = 0; p < 4; ++p) {
                int r = lr + p * 16;
                int grow = row0 + r; if (grow > N_NODES - 1) grow = N_NODES - 1;
                float4 v = *(const float4*)(X + (size_t)grow * FEAT + kbase + lc * 4);
                float vv[4] = {v.x, v.y, v.z, v.w};
#pragma unroll
                for (int i = 0; i < 4; ++i) {
                    int ii = (i + lc) & 3;       // rotate to spread banks
                    at[lc * 4 + ii][r] = vv[ii];
                }
            }
        }
        {
            int jf = tid & 15, kk0 = tid >> 4;
#pragma unroll
            for (int p = 0; p < 4; ++p) {
                int kk = kk0 + p * 16;
                *(float4*)&bs[kk][jf * 4] =
                    *(const float4*)(B + (size_t)(kbase + kk) * OUT + jf * 4);
            }
        }
        __syncthreads();
#pragma unroll 8
        for (int kk = 0; kk < 64; ++kk) {
            float4 a = *(const float4*)&at[kk][ty * 4];
            float4 b = *(const float4*)&bs[kk][tx * 4];
            float av[4] = {a.x, a.y, a.z, a.w};
            float bv[4] = {b.x, b.y, b.z, b.w};
#pragma unroll
            for (int r = 0; r < 4; ++r)
#pragma unroll
                for (int c = 0; c < 4; ++c)
                    acc[r][c] = fmaf(av[r], bv[c], acc[r][c]);
        }
        __syncthreads();
    }

    float4 bj = *(const float4*)(bias + tx * 4);
    float bjv[4] = {bj.x, bj.y, bj.z, bj.w};
#pragma unroll
    for (int r = 0; r < 4; ++r) {
        int grow = row0 + ty * 4 + r;
        if (grow < N_NODES) {
            float o[4];
#pragma unroll
            for (int c = 0; c < 4; ++c) o[c] = acc[r][c] + bjv[c];
            size_t off = (size_t)grow * OUT + tx * 4;
            *(uint2*)(h0 + off) = make_uint2(pack_bf16(o[0], o[1]), pack_bf16(o[2], o[3]));
        }
    }
}

// ---------------- init per-bucket allocator cursors -------------------------
__global__ __launch_bounds__(256) void init_k(int* __restrict__ bcur) {
    int t = threadIdx.x;
    if (t < NBUCK) bcur[t] = t * CAP;
}

// ---------------- CSR build pass 1: multisplit scatter into buckets ---------
// entry: .x = src(17b) | dstlow(10b)<<17 ; .y = weight bits
__global__ __launch_bounds__(256) void fill_p1(
    const int* __restrict__ erow, const int* __restrict__ ecol,
    const float* __restrict__ ew,
    int* __restrict__ bcur, int2* __restrict__ meta_tmp)
{
    __shared__ int2 stage[2 * EPB];
    __shared__ unsigned char bkt[2 * EPB];
    __shared__ int lcnt[256], loff[256], gbase[256], cur[256];
    __shared__ int sdata[256];
    const int tid = threadIdx.x;
    const int base = blockIdx.x * EPB;
    const int n = min(EPB, N_EDGES - base);

    int r[8], c[8], wb[8];
    lcnt[tid] = 0;
    __syncthreads();
#pragma unroll
    for (int k = 0; k < 8; ++k) {
        int i = k * 256 + tid;
        if (i < n) {
            int e = base + i;
            r[k] = erow[e];
            c[k] = ecol[e];
            wb[k] = __float_as_int(ew[e]);
            atomicAdd(&lcnt[r[k] >> 10], 1);
            atomicAdd(&lcnt[(NPAD + c[k]) >> 10], 1);
        } else {
            r[k] = -1;
        }
    }
    __syncthreads();
    sdata[tid] = lcnt[tid];
    __syncthreads();
    for (int off = 1; off < 256; off <<= 1) {
        int t = (tid >= off) ? sdata[tid - off] : 0;
        __syncthreads();
        sdata[tid] += t;
        __syncthreads();
    }
    loff[tid] = sdata[tid] - lcnt[tid];
    cur[tid] = loff[tid];
    gbase[tid] = (lcnt[tid] > 0) ? atomicAdd(&bcur[tid], lcnt[tid]) : 0;
    __syncthreads();
#pragma unroll
    for (int k = 0; k < 8; ++k) {
        if (r[k] >= 0) {
            int bs_ = r[k] >> 10;
            int l = atomicAdd(&cur[bs_], 1);
            stage[l] = make_int2(c[k] | ((r[k] & 1023) << 17), wb[k]);
            bkt[l] = (unsigned char)bs_;
            int ut = NPAD + c[k];
            int bt_ = ut >> 10;
            int l2 = atomicAdd(&cur[bt_], 1);
            stage[l2] = make_int2(r[k] | ((ut & 1023) << 17), wb[k]);
            bkt[l2] = (unsigned char)bt_;
        }
    }
    __syncthreads();
    const int tot = 2 * n;
    for (int i = tid; i < tot; i += 256) {
        int b = bkt[i];
        meta_tmp[(size_t)gbase[b] + (i - loff[b])] = stage[i];
    }
}

// ---------------- CSR build pass 2: within-bucket sort + rowptr -------------
// meta uses the SAME sparse per-bucket segments [b*CAP, bcur[b]) as meta_tmp
__global__ __launch_bounds__(256) void fill_p2(
    const int* __restrict__ bcur,
    const int2* __restrict__ meta_tmp,
    int2* __restrict__ meta, int* __restrict__ rowptr)
{
    __shared__ int cnt[1024];
    __shared__ int sdata[256];
    const int tid = threadIdx.x;
    const int b = blockIdx.x;
    const int seg0 = b * CAP;
    const int seg1 = bcur[b];

    for (int i = tid; i < 1024; i += 256) cnt[i] = 0;
    __syncthreads();
    for (int j = seg0 + tid; j < seg1; j += 256) {
        int2 e = meta_tmp[j];
        atomicAdd(&cnt[(e.x >> 17) & 1023], 1);
    }
    __syncthreads();
    int4 v = *(int4*)&cnt[tid * 4];
    int tsum = v.x + v.y + v.z + v.w;
    sdata[tid] = tsum;
    __syncthreads();
    for (int off = 1; off < 256; off <<= 1) {
        int t = (tid >= off) ? sdata[tid - off] : 0;
        __syncthreads();
        sdata[tid] += t;
        __syncthreads();
    }
    int excl = sdata[tid] - tsum;
    int4 o;
    o.x = seg0 + excl;
    o.y = o.x + v.x;
    o.z = o.y + v.y;
    o.w = o.z + v.z;
    *(int4*)(rowptr + b * RPS + tid * 4) = o;    // row starts (absolute into meta)
    *(int4*)&cnt[tid * 4] = o;                   // cursors
    if (tid == 0) rowptr[b * RPS + 1024] = seg1; // bucket end slot
    __syncthreads();
    for (int j = seg0 + tid; j < seg1; j += 256) {
        int2 e = meta_tmp[j];
        int pos = atomicAdd(&cnt[(e.x >> 17) & 1023], 1);
        meta[pos] = make_int2(e.x & 0x1ffff, e.y);
    }
}

// ---------------- pure SPMM: eighth-wave per edge, bf16, 64 cols ------------
// lane = (q: edge slot 0..7) * 8 + (sl: col group 0..7)
// one uint4 (16B = 8 bf16) gather per lane covers the row with 8 lanes;
// 8 edges per wave-iter with ONE gather + ONE meta load per lane.
__global__ __launch_bounds__(256) void spmm_k(
    const int* __restrict__ rowptr,
    const int2* __restrict__ meta,
    const ushort_t* __restrict__ xs, const ushort_t* __restrict__ xt,
    ushort_t* __restrict__ ns, ushort_t* __restrict__ nt)
{
    const int unit = blockIdx.x * 4 + (threadIdx.x >> 6);   // one wave per unit
    const int lane = threadIdx.x & 63;
    const int q  = lane >> 3;         // edge slot 0..7
    const int sl = lane & 7;          // col group 0..7

    const ushort_t* x; ushort_t* nxt;
    int node;
    if (unit < NPAD) {
        node = unit;
        if (node >= N_NODES) return;
        x = xs; nxt = ns;
    } else {
        node = unit - NPAD;
        if (node >= N_NODES) return;
        x = xt; nxt = nt;
    }

    const int rbase = (unit >> 10) * RPS + (unit & 1023);
    const int start = rowptr[rbase];
    const int end   = rowptr[rbase + 1];

    float a0 = 0.f, a1 = 0.f, a2 = 0.f, a3 = 0.f;
    float a4 = 0.f, a5 = 0.f, a6 = 0.f, a7 = 0.f;
    const int coff = sl * 8;          // 8 bf16 cols per lane

    int jb = start;
    for (; jb + 7 < end; jb += 8) {          // 8 edges per iter, unmasked
        // meta entry as one 8B NT load: low32 = src|dstlow, high32 = w bits
        long long mw = __builtin_nontemporal_load(
            (const long long*)(meta + jb + q));
        int s = (int)mw & 0x1ffff;
        float w = __int_as_float((int)((unsigned long long)mw >> 32));
        uint4 u = *(const uint4*)(x + ((size_t)s << 6) + coff);
        a0 = fmaf(w, bflo(u.x), a0);
        a1 = fmaf(w, bfhi(u.x), a1);
        a2 = fmaf(w, bflo(u.y), a2);
        a3 = fmaf(w, bfhi(u.y), a3);
        a4 = fmaf(w, bflo(u.z), a4);
        a5 = fmaf(w, bfhi(u.z), a5);
        a6 = fmaf(w, bflo(u.w), a6);
        a7 = fmaf(w, bfhi(u.w), a7);
    }
    for (; jb < end; jb += 8) {              // masked tail group
        int jj = jb + q;
        bool valid = jj < end;
        long long mw = __builtin_nontemporal_load(
            (const long long*)(meta + (valid ? jj : start)));
        int s = (int)mw & 0x1ffff;
        float w = valid ? __int_as_float((int)((unsigned long long)mw >> 32)) : 0.f;
        uint4 u = *(const uint4*)(x + ((size_t)s << 6) + coff);
        a0 = fmaf(w, bflo(u.x), a0);
        a1 = fmaf(w, bfhi(u.x), a1);
        a2 = fmaf(w, bflo(u.y), a2);
        a3 = fmaf(w, bfhi(u.y), a3);
        a4 = fmaf(w, bflo(u.z), a4);
        a5 = fmaf(w, bfhi(u.z), a5);
        a6 = fmaf(w, bflo(u.w), a6);
        a7 = fmaf(w, bfhi(u.w), a7);
    }

    // fold the 8 edge-slot partials (lanes differ in bits 3..5)
#pragma unroll
    for (int d = 8; d < 64; d <<= 1) {
        a0 += __shfl_xor(a0, d, 64);
        a1 += __shfl_xor(a1, d, 64);
        a2 += __shfl_xor(a2, d, 64);
        a3 += __shfl_xor(a3, d, 64);
        a4 += __shfl_xor(a4, d, 64);
        a5 += __shfl_xor(a5, d, 64);
        a6 += __shfl_xor(a6, d, 64);
        a7 += __shfl_xor(a7, d, 64);
    }

    if (q == 0) {
        *(uint4*)(nxt + ((size_t)node << 6) + coff) =
            make_uint4(pack_bf16(a0, a1), pack_bf16(a2, a3),
                       pack_bf16(a4, a5), pack_bf16(a6, a7));
    }
}

// ---------------- combine: out = Σ ws[h]·hs_h + Σ wt[h]·ht_h + bn ----------
__global__ __launch_bounds__(256) void combine_k(
    const ushort_t* __restrict__ s0, const ushort_t* __restrict__ s1,
    const ushort_t* __restrict__ s2, const ushort_t* __restrict__ s3,
    const ushort_t* __restrict__ t0, const ushort_t* __restrict__ t1,
    const ushort_t* __restrict__ t2, const ushort_t* __restrict__ t3,
    const float* __restrict__ wsv, const float* __restrict__ wtv,
    const float* __restrict__ bn,
    float* __restrict__ out)
{
    const int gid = blockIdx.x * 256 + threadIdx.x;   // one per 4 cols
    if (gid >= N_NODES * (OUT / 4)) return;
    const size_t off = (size_t)gid * 4;

    float4 b = ((const float4*)bn)[gid & (OUT / 4 - 1)];
    float acc[4] = {b.x, b.y, b.z, b.w};

    const ushort_t* bufs[8] = {s0, s1, s2, s3, t0, t1, t2, t3};
    float w[8];
#pragma unroll
    for (int h = 0; h < 4; ++h) { w[h] = wsv[h]; w[4 + h] = wtv[h]; }

#pragma unroll
    for (int h = 0; h < 8; ++h) {
        ushort4 u = *(const ushort4*)(bufs[h] + off);
        acc[0] = fmaf(w[h], bf2f(u.x), acc[0]);
        acc[1] = fmaf(w[h], bf2f(u.y), acc[1]);
        acc[2] = fmaf(w[h], bf2f(u.z), acc[2]);
        acc[3] = fmaf(w[h], bf2f(u.w), acc[3]);
    }
    *(float4*)(out + off) = make_float4(acc[0], acc[1], acc[2], acc[3]);
}

extern "C" void kernel_launch(void* const* d_in, const int* in_sizes, int n_in,
                              void* d_out, int out_size, void* d_ws, size_t ws_size,
                              hipStream_t stream) {
    const float* fsrc = (const float*)d_in[0];
    const float* ftgt = (const float*)d_in[1];
    const int*   erow = (const int*)d_in[2];
    const int*   ecol = (const int*)d_in[3];
    const float* ew   = (const float*)d_in[4];
    const float* Wsrc = (const float*)d_in[5];
    const float* bsrc = (const float*)d_in[6];
    const float* Wtgt = (const float*)d_in[7];
    const float* btgt = (const float*)d_in[8];
    const float* ws   = (const float*)d_in[9];
    const float* wt   = (const float*)d_in[10];
    const float* Wn   = (const float*)d_in[11];
    const float* bn   = (const float*)d_in[12];
    float* out = (float*)d_out;

    const size_t buf = (size_t)N_NODES * OUT;   // elements per hop buffer (64-dim)
    char* p = (char*)d_ws;
    ushort_t* hs[4]; ushort_t* ht[4];
    for (int h = 0; h < 4; ++h) {
        hs[h] = (ushort_t*)p; p += buf * 2;
        ht[h] = (ushort_t*)p; p += buf * 2;
    }
    int2* meta     = (int2*)p;  p += (size_t)NBUCK * CAP * 8;   // sparse layout!
    int2* meta_tmp = (int2*)p;  p += (size_t)NBUCK * CAP * 8;
    int* rowptr    = (int*)p;   p += (size_t)NBUCK * RPS * 4 + 64;
    float* Wc      = (float*)p; p += 512 * OUT * 4;
    float* bc      = (float*)p; p += 128 * 4;
    int* bcur      = (int*)p;   p += 256 * 4;

    const int eblocks = (N_EDGES + EPB - 1) / EPB;   // 1563
    const int gblocks = (N_NODES + 63) / 64;         // 1563

    // fold output projection into input weights
    wcomb_k<<<514, 64, 0, stream>>>(Wsrc, Wtgt, bsrc, btgt, Wn, Wc, bc);

    // input GEMMs -> bf16 hop-0 buffers (already projected to 64 dims)
    gemm_in<<<gblocks, 256, 0, stream>>>(fsrc, Wc, bc, hs[0]);
    gemm_in<<<gblocks, 256, 0, stream>>>(ftgt, Wc + 256 * OUT, bc + OUT, ht[0]);

    // CSR build: fixed-capacity buckets (no counting pre-pass)
    init_k<<<1, 256, 0, stream>>>(bcur);
    fill_p1<<<eblocks, 256, 0, stream>>>(erow, ecol, ew, bcur, meta_tmp);
    fill_p2<<<NBUCK, 256, 0, stream>>>(bcur, meta_tmp, meta, rowptr);

    // 3 hops, both directions per launch
    const int sblocks = NTOT / 4;
    for (int h = 1; h <= HOPS; ++h) {
        spmm_k<<<sblocks, 256, 0, stream>>>(rowptr, meta,
                                            hs[h - 1], ht[h - 1], hs[h], ht[h]);
    }

    // final weighted combine + bias
    combine_k<<<(N_NODES * (OUT / 4) + 255) / 256, 256, 0, stream>>>(
        hs[0], hs[1], hs[2], hs[3], ht[0], ht[1], ht[2], ht[3], ws, wt, bn, out);
}

// Round 9
// 697.553 us; speedup vs baseline: 1.1109x; 1.1109x over previous
//
#include <hip/hip_runtime.h>

#define N_NODES 100000
#define N_EDGES 3200000
#define FEAT 256
#define HID 128
#define OUT 64
#define HOPS 3

#define NPAD 100352                      // 98*1024, >= N_NODES
#define NTOT (2 * NPAD)                  // combined s|t dst-unit space = 200704
#define NBUCK 196                        // NTOT / 1024 buckets (1024 units each)
#define CAP 36864                        // fixed bucket capacity (mean 32768, +22 sigma)
#define RPS 1028                         // rowptr stride per bucket (1024 starts + end slot)
#define EPB 2048                         // edges per block in CSR-build passes

typedef unsigned short ushort_t;

__device__ __forceinline__ float bf2f(ushort_t u) {
    return __uint_as_float(((unsigned)u) << 16);
}
__device__ __forceinline__ float bflo(unsigned u) { return __uint_as_float(u << 16); }
__device__ __forceinline__ float bfhi(unsigned u) { return __uint_as_float(u & 0xffff0000u); }
__device__ __forceinline__ unsigned pack_bf16(float a, float b) {
    unsigned ua = __float_as_uint(a);
    unsigned ub = __float_as_uint(b);
    ua += 0x7fffu + ((ua >> 16) & 1u);
    ub += 0x7fffu + ((ub >> 16) & 1u);
    return (ua >> 16) | (ub & 0xffff0000u);
}

// ---------------- weight fold: Wc = W_{src,tgt} @ Wn_half ; bc = b @ Wn_half
__global__ __launch_bounds__(64) void wcomb_k(
    const float* __restrict__ Wsrc, const float* __restrict__ Wtgt,
    const float* __restrict__ bsrc, const float* __restrict__ btgt,
    const float* __restrict__ Wn,     // [2*HID, OUT]
    float* __restrict__ Wc,           // [512, 64]
    float* __restrict__ bc)           // [128]
{
    const int blk = blockIdx.x;
    const int j = threadIdx.x;
    if (blk < 512) {
        const float* Wsel = (blk < 256) ? Wsrc : Wtgt;
        const int i = blk & 255;
        const int koff = (blk < 256) ? 0 : HID;
        float acc = 0.f;
        for (int k = 0; k < HID; ++k)
            acc = fmaf(Wsel[i * HID + k], Wn[(koff + k) * OUT + j], acc);
        Wc[blk * OUT + j] = acc;
    } else {
        const float* bsel = (blk == 512) ? bsrc : btgt;
        const int koff = (blk == 512) ? 0 : HID;
        float acc = 0.f;
        for (int k = 0; k < HID; ++k)
            acc = fmaf(bsel[k], Wn[(koff + k) * OUT + j], acc);
        bc[(blk - 512) * OUT + j] = acc;
    }
}

// ---------------- input GEMM: h0 = bf16(X @ Wc + bc) ------------------------
__global__ __launch_bounds__(256) void gemm_in(
    const float* __restrict__ X,      // [N, FEAT]
    const float* __restrict__ B,      // [FEAT, OUT] folded weights
    const float* __restrict__ bias,   // [OUT] folded bias
    ushort_t* __restrict__ h0)        // [N, OUT] bf16
{
    __shared__ __align__(16) float at[64][76];   // A transposed [kk][row]
    __shared__ __align__(16) float bs[64][OUT];  // B chunk [kk][j]
    const int tid = threadIdx.x;
    const int tx = tid & 15;          // cols tx*4 .. tx*4+3
    const int ty = tid >> 4;          // rows ty*4 .. ty*4+3
    const int row0 = blockIdx.x * 64;

    float acc[4][4];
#pragma unroll
    for (int r = 0; r < 4; ++r)
#pragma unroll
        for (int c = 0; c < 4; ++c) acc[r][c] = 0.f;

    for (int chunk = 0; chunk < 4; ++chunk) {
        const int kbase = chunk * 64;
        {
            int lc = tid & 15, lr = tid >> 4;
#pragma unroll
            for (int p = 0; p < 4; ++p) {
                int r = lr + p * 16;
                int grow = row0 + r; if (grow > N_NODES - 1) grow = N_NODES - 1;
                float4 v = *(const float4*)(X + (size_t)grow * FEAT + kbase + lc * 4);
                float vv[4] = {v.x, v.y, v.z, v.w};
#pragma unroll
                for (int i = 0; i < 4; ++i) {
                    int ii = (i + lc) & 3;       // rotate to spread banks
                    at[lc * 4 + ii][r] = vv[ii];
                }
            }
        }
        {
            int jf = tid & 15, kk0 = tid >> 4;
#pragma unroll
            for (int p = 0; p < 4; ++p) {
                int kk = kk0 + p * 16;
                *(float4*)&bs[kk][jf * 4] =
                    *(const float4*)(B + (size_t)(kbase + kk) * OUT + jf * 4);
            }
        }
        __syncthreads();
#pragma unroll 8
        for (int kk = 0; kk < 64; ++kk) {
            float4 a = *(const float4*)&at[kk][ty * 4];
            float4 b = *(const float4*)&bs[kk][tx * 4];
            float av[4] = {a.x, a.y, a.z, a.w};
            float bv[4] = {b.x, b.y, b.z, b.w};
#pragma unroll
            for (int r = 0; r < 4; ++r)
#pragma unroll
                for (int c = 0; c < 4; ++c)
                    acc[r][c] = fmaf(av[r], bv[c], acc[r][c]);
        }
        __syncthreads();
    }

    float4 bj = *(const float4*)(bias + tx * 4);
    float bjv[4] = {bj.x, bj.y, bj.z, bj.w};
#pragma unroll
    for (int r = 0; r < 4; ++r) {
        int grow = row0 + ty * 4 + r;
        if (grow < N_NODES) {
            float o[4];
#pragma unroll
            for (int c = 0; c < 4; ++c) o[c] = acc[r][c] + bjv[c];
            size_t off = (size_t)grow * OUT + tx * 4;
            *(uint2*)(h0 + off) = make_uint2(pack_bf16(o[0], o[1]), pack_bf16(o[2], o[3]));
        }
    }
}

// ---------------- init per-bucket allocator cursors -------------------------
__global__ __launch_bounds__(256) void init_k(int* __restrict__ bcur) {
    int t = threadIdx.x;
    if (t < NBUCK) bcur[t] = t * CAP;
}

// ---------------- CSR build pass 1: multisplit scatter into buckets ---------
// entry: .x = src(17b) | dstlow(10b)<<17 ; .y = weight bits
__global__ __launch_bounds__(256) void fill_p1(
    const int* __restrict__ erow, const int* __restrict__ ecol,
    const float* __restrict__ ew,
    int* __restrict__ bcur, int2* __restrict__ meta_tmp)
{
    __shared__ int2 stage[2 * EPB];
    __shared__ unsigned char bkt[2 * EPB];
    __shared__ int lcnt[256], loff[256], gbase[256], cur[256];
    __shared__ int sdata[256];
    const int tid = threadIdx.x;
    const int base = blockIdx.x * EPB;
    const int n = min(EPB, N_EDGES - base);

    int r[8], c[8], wb[8];
    lcnt[tid] = 0;
    __syncthreads();
#pragma unroll
    for (int k = 0; k < 8; ++k) {
        int i = k * 256 + tid;
        if (i < n) {
            int e = base + i;
            r[k] = erow[e];
            c[k] = ecol[e];
            wb[k] = __float_as_int(ew[e]);
            atomicAdd(&lcnt[r[k] >> 10], 1);
            atomicAdd(&lcnt[(NPAD + c[k]) >> 10], 1);
        } else {
            r[k] = -1;
        }
    }
    __syncthreads();
    sdata[tid] = lcnt[tid];
    __syncthreads();
    for (int off = 1; off < 256; off <<= 1) {
        int t = (tid >= off) ? sdata[tid - off] : 0;
        __syncthreads();
        sdata[tid] += t;
        __syncthreads();
    }
    loff[tid] = sdata[tid] - lcnt[tid];
    cur[tid] = loff[tid];
    gbase[tid] = (lcnt[tid] > 0) ? atomicAdd(&bcur[tid], lcnt[tid]) : 0;
    __syncthreads();
#pragma unroll
    for (int k = 0; k < 8; ++k) {
        if (r[k] >= 0) {
            int bs_ = r[k] >> 10;
            int l = atomicAdd(&cur[bs_], 1);
            stage[l] = make_int2(c[k] | ((r[k] & 1023) << 17), wb[k]);
            bkt[l] = (unsigned char)bs_;
            int ut = NPAD + c[k];
            int bt_ = ut >> 10;
            int l2 = atomicAdd(&cur[bt_], 1);
            stage[l2] = make_int2(r[k] | ((ut & 1023) << 17), wb[k]);
            bkt[l2] = (unsigned char)bt_;
        }
    }
    __syncthreads();
    const int tot = 2 * n;
    for (int i = tid; i < tot; i += 256) {
        int b = bkt[i];
        meta_tmp[(size_t)gbase[b] + (i - loff[b])] = stage[i];
    }
}

// ---------------- CSR build pass 2: within-bucket sort + rowptr -------------
// meta uses the SAME sparse per-bucket segments [b*CAP, bcur[b]) as meta_tmp
__global__ __launch_bounds__(256) void fill_p2(
    const int* __restrict__ bcur,
    const int2* __restrict__ meta_tmp,
    int2* __restrict__ meta, int* __restrict__ rowptr)
{
    __shared__ int cnt[1024];
    __shared__ int sdata[256];
    const int tid = threadIdx.x;
    const int b = blockIdx.x;
    const int seg0 = b * CAP;
    const int seg1 = bcur[b];

    for (int i = tid; i < 1024; i += 256) cnt[i] = 0;
    __syncthreads();
    for (int j = seg0 + tid; j < seg1; j += 256) {
        int2 e = meta_tmp[j];
        atomicAdd(&cnt[(e.x >> 17) & 1023], 1);
    }
    __syncthreads();
    int4 v = *(int4*)&cnt[tid * 4];
    int tsum = v.x + v.y + v.z + v.w;
    sdata[tid] = tsum;
    __syncthreads();
    for (int off = 1; off < 256; off <<= 1) {
        int t = (tid >= off) ? sdata[tid - off] : 0;
        __syncthreads();
        sdata[tid] += t;
        __syncthreads();
    }
    int excl = sdata[tid] - tsum;
    int4 o;
    o.x = seg0 + excl;
    o.y = o.x + v.x;
    o.z = o.y + v.y;
    o.w = o.z + v.z;
    *(int4*)(rowptr + b * RPS + tid * 4) = o;    // row starts (absolute into meta)
    *(int4*)&cnt[tid * 4] = o;                   // cursors
    if (tid == 0) rowptr[b * RPS + 1024] = seg1; // bucket end slot
    __syncthreads();
    for (int j = seg0 + tid; j < seg1; j += 256) {
        int2 e = meta_tmp[j];
        int pos = atomicAdd(&cnt[(e.x >> 17) & 1023], 1);
        meta[pos] = make_int2(e.x & 0x1ffff, e.y);
    }
}

// ---------------- pure SPMM: quarter-wave per edge, 16-edge pipelined -------
// lane = (q: edge slot 0..3) * 16 + (sl: col group 0..15); uint2 per lane.
// 16 edges per iter = 4 meta + 4 gathers in flight; next metas prefetched
// while current gathers are outstanding (gather-latency-bound -> max MLP).
__global__ __launch_bounds__(256) void spmm_k(
    const int* __restrict__ rowptr,
    const int2* __restrict__ meta,
    const ushort_t* __restrict__ xs, const ushort_t* __restrict__ xt,
    ushort_t* __restrict__ ns, ushort_t* __restrict__ nt)
{
    const int unit = blockIdx.x * 4 + (threadIdx.x >> 6);   // one wave per unit
    const int lane = threadIdx.x & 63;
    const int q  = lane >> 4;
    const int sl = lane & 15;

    const ushort_t* x; ushort_t* nxt;
    int node;
    if (unit < NPAD) {
        node = unit;
        if (node >= N_NODES) return;
        x = xs; nxt = ns;
    } else {
        node = unit - NPAD;
        if (node >= N_NODES) return;
        x = xt; nxt = nt;
    }

    const int rbase = (unit >> 10) * RPS + (unit & 1023);
    const int start = rowptr[rbase];
    const int end   = rowptr[rbase + 1];

    float a0 = 0.f, a1 = 0.f, a2 = 0.f, a3 = 0.f;
    const int coff = sl * 4;

    int jb = start;
    int2 m0, m1, m2, m3;
    bool have = (jb + 15 < end);
    if (have) {
        m0 = meta[jb + q];
        m1 = meta[jb + 4 + q];
        m2 = meta[jb + 8 + q];
        m3 = meta[jb + 12 + q];
    }
    while (have) {
        // issue 4 independent gathers for current metas
        uint2 u0 = *(const uint2*)(x + ((size_t)(m0.x & 0x1ffff) << 6) + coff);
        uint2 u1 = *(const uint2*)(x + ((size_t)(m1.x & 0x1ffff) << 6) + coff);
        uint2 u2 = *(const uint2*)(x + ((size_t)(m2.x & 0x1ffff) << 6) + coff);
        uint2 u3 = *(const uint2*)(x + ((size_t)(m3.x & 0x1ffff) << 6) + coff);
        float w0 = __int_as_float(m0.y), w1 = __int_as_float(m1.y);
        float w2 = __int_as_float(m2.y), w3 = __int_as_float(m3.y);

        // prefetch next iteration's metas while gathers are in flight
        const int jn = jb + 16;
        have = (jn + 15 < end);
        if (have) {
            m0 = meta[jn + q];
            m1 = meta[jn + 4 + q];
            m2 = meta[jn + 8 + q];
            m3 = meta[jn + 12 + q];
        }
        jb = jn;

        a0 = fmaf(w0, bflo(u0.x), a0);
        a1 = fmaf(w0, bfhi(u0.x), a1);
        a2 = fmaf(w0, bflo(u0.y), a2);
        a3 = fmaf(w0, bfhi(u0.y), a3);
        a0 = fmaf(w1, bflo(u1.x), a0);
        a1 = fmaf(w1, bfhi(u1.x), a1);
        a2 = fmaf(w1, bflo(u1.y), a2);
        a3 = fmaf(w1, bfhi(u1.y), a3);
        a0 = fmaf(w2, bflo(u2.x), a0);
        a1 = fmaf(w2, bfhi(u2.x), a1);
        a2 = fmaf(w2, bflo(u2.y), a2);
        a3 = fmaf(w2, bfhi(u2.y), a3);
        a0 = fmaf(w3, bflo(u3.x), a0);
        a1 = fmaf(w3, bfhi(u3.x), a1);
        a2 = fmaf(w3, bflo(u3.y), a2);
        a3 = fmaf(w3, bfhi(u3.y), a3);
    }
    for (; jb < end; jb += 4) {              // masked tail groups (4 edges)
        int jj = jb + q;
        bool valid = jj < end;
        int2 m = meta[valid ? jj : start];
        int s = m.x & 0x1ffff;
        float w = valid ? __int_as_float(m.y) : 0.f;
        uint2 u = *(const uint2*)(x + ((size_t)s << 6) + coff);
        a0 = fmaf(w, bflo(u.x), a0);
        a1 = fmaf(w, bfhi(u.x), a1);
        a2 = fmaf(w, bflo(u.y), a2);
        a3 = fmaf(w, bfhi(u.y), a3);
    }

    // fold the 4 edge-slot partials (lanes differ in bits 4-5)
    a0 += __shfl_xor(a0, 16, 64);
    a1 += __shfl_xor(a1, 16, 64);
    a2 += __shfl_xor(a2, 16, 64);
    a3 += __shfl_xor(a3, 16, 64);
    a0 += __shfl_xor(a0, 32, 64);
    a1 += __shfl_xor(a1, 32, 64);
    a2 += __shfl_xor(a2, 32, 64);
    a3 += __shfl_xor(a3, 32, 64);

    if (q == 0) {
        *(uint2*)(nxt + ((size_t)node << 6) + coff) =
            make_uint2(pack_bf16(a0, a1), pack_bf16(a2, a3));
    }
}

// ---------------- combine: out = Σ ws[h]·hs_h + Σ wt[h]·ht_h + bn ----------
__global__ __launch_bounds__(256) void combine_k(
    const ushort_t* __restrict__ s0, const ushort_t* __restrict__ s1,
    const ushort_t* __restrict__ s2, const ushort_t* __restrict__ s3,
    const ushort_t* __restrict__ t0, const ushort_t* __restrict__ t1,
    const ushort_t* __restrict__ t2, const ushort_t* __restrict__ t3,
    const float* __restrict__ wsv, const float* __restrict__ wtv,
    const float* __restrict__ bn,
    float* __restrict__ out)
{
    const int gid = blockIdx.x * 256 + threadIdx.x;   // one per 4 cols
    if (gid >= N_NODES * (OUT / 4)) return;
    const size_t off = (size_t)gid * 4;

    float4 b = ((const float4*)bn)[gid & (OUT / 4 - 1)];
    float acc[4] = {b.x, b.y, b.z, b.w};

    const ushort_t* bufs[8] = {s0, s1, s2, s3, t0, t1, t2, t3};
    float w[8];
#pragma unroll
    for (int h = 0; h < 4; ++h) { w[h] = wsv[h]; w[4 + h] = wtv[h]; }

#pragma unroll
    for (int h = 0; h < 8; ++h) {
        ushort4 u = *(const ushort4*)(bufs[h] + off);
        acc[0] = fmaf(w[h], bf2f(u.x), acc[0]);
        acc[1] = fmaf(w[h], bf2f(u.y), acc[1]);
        acc[2] = fmaf(w[h], bf2f(u.z), acc[2]);
        acc[3] = fmaf(w[h], bf2f(u.w), acc[3]);
    }
    *(float4*)(out + off) = make_float4(acc[0], acc[1], acc[2], acc[3]);
}

extern "C" void kernel_launch(void* const* d_in, const int* in_sizes, int n_in,
                              void* d_out, int out_size, void* d_ws, size_t ws_size,
                              hipStream_t stream) {
    const float* fsrc = (const float*)d_in[0];
    const float* ftgt = (const float*)d_in[1];
    const int*   erow = (const int*)d_in[2];
    const int*   ecol = (const int*)d_in[3];
    const float* ew   = (const float*)d_in[4];
    const float* Wsrc = (const float*)d_in[5];
    const float* bsrc = (const float*)d_in[6];
    const float* Wtgt = (const float*)d_in[7];
    const float* btgt = (const float*)d_in[8];
    const float* ws   = (const float*)d_in[9];
    const float* wt   = (const float*)d_in[10];
    const float* Wn   = (const float*)d_in[11];
    const float* bn   = (const float*)d_in[12];
    float* out = (float*)d_out;

    const size_t buf = (size_t)N_NODES * OUT;   // elements per hop buffer (64-dim)
    char* p = (char*)d_ws;
    ushort_t* hs[4]; ushort_t* ht[4];
    for (int h = 0; h < 4; ++h) {
        hs[h] = (ushort_t*)p; p += buf * 2;
        ht[h] = (ushort_t*)p; p += buf * 2;
    }
    int2* meta     = (int2*)p;  p += (size_t)NBUCK * CAP * 8;   // sparse layout!
    int2* meta_tmp = (int2*)p;  p += (size_t)NBUCK * CAP * 8;
    int* rowptr    = (int*)p;   p += (size_t)NBUCK * RPS * 4 + 64;
    float* Wc      = (float*)p; p += 512 * OUT * 4;
    float* bc      = (float*)p; p += 128 * 4;
    int* bcur      = (int*)p;   p += 256 * 4;

    const int eblocks = (N_EDGES + EPB - 1) / EPB;   // 1563
    const int gblocks = (N_NODES + 63) / 64;         // 1563

    // fold output projection into input weights
    wcomb_k<<<514, 64, 0, stream>>>(Wsrc, Wtgt, bsrc, btgt, Wn, Wc, bc);

    // input GEMMs -> bf16 hop-0 buffers (already projected to 64 dims)
    gemm_in<<<gblocks, 256, 0, stream>>>(fsrc, Wc, bc, hs[0]);
    gemm_in<<<gblocks, 256, 0, stream>>>(ftgt, Wc + 256 * OUT, bc + OUT, ht[0]);

    // CSR build: fixed-capacity buckets (no counting pre-pass)
    init_k<<<1, 256, 0, stream>>>(bcur);
    fill_p1<<<eblocks, 256, 0, stream>>>(erow, ecol, ew, bcur, meta_tmp);
    fill_p2<<<NBUCK, 256, 0, stream>>>(bcur, meta_tmp, meta, rowptr);

    // 3 hops, both directions per launch
    const int sblocks = NTOT / 4;
    for (int h = 1; h <= HOPS; ++h) {
        spmm_k<<<sblocks, 256, 0, stream>>>(rowptr, meta,
                                            hs[h - 1], ht[h - 1], hs[h], ht[h]);
    }

    // final weighted combine + bias
    combine_k<<<(N_NODES * (OUT / 4) + 255) / 256, 256, 0, stream>>>(
        hs[0], hs[1], hs[2], hs[3], ht[0], ht[1], ht[2], ht[3], ws, wt, bn, out);
}